// Round 3
// baseline (460.386 us; speedup 1.0000x reference)
//
#include <hip/hip_runtime.h>

// InstantNGP MLP: (N,32) -> [Linear+ReLU]x3 -> Linear -> (N,16), all fp32.
//
// Transposed MFMA chain, 3-product bf16 hi/lo split (fp32-accurate; absmax
// 9.8e-4 PASS in R1/R2). A = W^T from LDS (bf16 hi+lo, stride 40/72 shorts,
// ds_read_b128); B = activations (col = sample); layer->layer handoff fully
// in-register via pack_hi16 + permlane32_swap.
//
// R3 vs R2 (codegen, not algorithm): R1/R2 burned ~750MB/launch of scratch
// traffic (VGPR pinned at 128 + spills / un-promoted allocas from the
// union+lambda formulation). This version:
//   - by-value structs of ext_vector types through __forceinline fns (SROA-safe)
//   - no unions (bit_cast), no lambdas, no address-taken local arrays
//   - amdgpu_waves_per_eu(2,3): allocator targets 3 waves/EU (~168 regs,
//     live set ~140), may relax to 2 (256) instead of spilling
//   - staging uses paired b32 LDS writes (halves the 8-way-conflict cost)

typedef float f32x4 __attribute__((ext_vector_type(4)));
typedef float f32x16 __attribute__((ext_vector_type(16)));
typedef short short8 __attribute__((ext_vector_type(8)));
typedef unsigned uint4v __attribute__((ext_vector_type(4)));

#define DEVFN static __device__ __forceinline__

// truncation split: hi = top16 bits of f32 (bf16 toward-zero), lo = exact residual
DEVFN unsigned pack_hi16(float a, float b) {
  return (__float_as_uint(a) >> 16) | (__float_as_uint(b) & 0xffff0000u);
}
DEVFN float lo_part(float a) {
  return a - __uint_as_float(__float_as_uint(a) & 0xffff0000u);
}
DEVFN short8 s8(uint4v v) { return __builtin_bit_cast(short8, v); }

struct F8 { uint4v h, l; };             // one B-frag (hi + lo), by value
struct Frags { F8 f0, f1, f2, f3; };    // full 64-feature B operand
struct U2 { unsigned lo, hi; };

DEVFN U2 half_swap(unsigned q, unsigned p, unsigned laneHi) {
#if __has_builtin(__builtin_amdgcn_permlane32_swap)
  (void)laneHi;
  auto r = __builtin_amdgcn_permlane32_swap(q, p, false, false);
  return U2{(unsigned)r[0], (unsigned)r[1]};
#else
  unsigned qs = (unsigned)__shfl_xor((int)q, 32, 64);
  unsigned ps = (unsigned)__shfl_xor((int)p, 32, 64);
  return U2{laneHi ? ps : q, laneHi ? p : qs};
#endif
}

// 8 C-regs of one 32x32 tile-half -> next-layer B frag (verified mapping)
DEVFN F8 mk_swap(float c0, float c1, float c2, float c3, float c4, float c5,
                 float c6, float c7, unsigned laneHi) {
  U2 a = half_swap(pack_hi16(c0, c1), pack_hi16(c4, c5), laneHi);
  U2 b = half_swap(pack_hi16(c2, c3), pack_hi16(c6, c7), laneHi);
  U2 c = half_swap(pack_hi16(lo_part(c0), lo_part(c1)),
                   pack_hi16(lo_part(c4), lo_part(c5)), laneHi);
  U2 d = half_swap(pack_hi16(lo_part(c2), lo_part(c3)),
                   pack_hi16(lo_part(c6), lo_part(c7)), laneHi);
  F8 f;
  f.h = (uint4v){a.lo, b.lo, a.hi, b.hi};
  f.l = (uint4v){c.lo, d.lo, c.hi, d.hi};
  return f;
}

// x row chunk (8 floats) -> layer-1 B frag (no cross-lane)
DEVFN F8 mk_direct(f32x4 a, f32x4 b) {
  F8 f;
  f.h = (uint4v){pack_hi16(a.x, a.y), pack_hi16(a.z, a.w),
                 pack_hi16(b.x, b.y), pack_hi16(b.z, b.w)};
  f.l = (uint4v){pack_hi16(lo_part(a.x), lo_part(a.y)),
                 pack_hi16(lo_part(a.z), lo_part(a.w)),
                 pack_hi16(lo_part(b.x), lo_part(b.y)),
                 pack_hi16(lo_part(b.z), lo_part(b.w))};
  return f;
}

DEVFN f32x16 mfma32(short8 a, short8 b, f32x16 c) {
  return __builtin_amdgcn_mfma_f32_32x32x16_bf16(a, b, c, 0, 0, 0);
}

// 3-product K=16 step: acc += W[off..].hi*B.lo + W.lo*B.hi + W.hi*B.hi
DEVFN f32x16 triple(const unsigned short* wh, const unsigned short* wl, int off,
                    F8 b, f32x16 acc) {
  short8 ah = *(const short8*)&wh[off];
  short8 al = *(const short8*)&wl[off];
  acc = mfma32(al, s8(b.h), acc);
  acc = mfma32(ah, s8(b.l), acc);
  acc = mfma32(ah, s8(b.h), acc);
  return acc;
}

DEVFN f32x16 bias16(const float* bsh, int boff, int hH) {
  f32x16 bi;
#pragma unroll
  for (int cq = 0; cq < 4; ++cq) {
    f32x4 bb = *(const f32x4*)&bsh[boff + 8 * cq + 4 * hH];
    bi[4 * cq + 0] = bb.x;
    bi[4 * cq + 1] = bb.y;
    bi[4 * cq + 2] = bb.z;
    bi[4 * cq + 3] = bb.w;
  }
  return bi;
}

DEVFN f32x16 relu16(f32x16 v) {
#pragma unroll
  for (int i = 0; i < 16; ++i) v[i] = fmaxf(v[i], 0.0f);
  return v;
}

// 64->64 layer: bias-init, 8x triple (stride 72), relu, rebuild frags
DEVFN Frags layer64(const unsigned short* wh, const unsigned short* wl,
                    const float* bsh, int boff, Frags in, int ln, int kb,
                    unsigned hH) {
  f32x16 a0 = bias16(bsh, boff, (int)hH);
  f32x16 a1 = bias16(bsh, boff + 32, (int)hH);
  const int r0 = ln * 72 + kb;
  const int r1 = (32 + ln) * 72 + kb;
  a0 = triple(wh, wl, r0 + 0, in.f0, a0);
  a0 = triple(wh, wl, r0 + 16, in.f1, a0);
  a0 = triple(wh, wl, r0 + 32, in.f2, a0);
  a0 = triple(wh, wl, r0 + 48, in.f3, a0);
  a1 = triple(wh, wl, r1 + 0, in.f0, a1);
  a1 = triple(wh, wl, r1 + 16, in.f1, a1);
  a1 = triple(wh, wl, r1 + 32, in.f2, a1);
  a1 = triple(wh, wl, r1 + 48, in.f3, a1);
  a0 = relu16(a0);
  a1 = relu16(a1);
  Frags o;
  o.f0 = mk_swap(a0[0], a0[1], a0[2], a0[3], a0[4], a0[5], a0[6], a0[7], hH);
  o.f1 = mk_swap(a0[8], a0[9], a0[10], a0[11], a0[12], a0[13], a0[14], a0[15], hH);
  o.f2 = mk_swap(a1[0], a1[1], a1[2], a1[3], a1[4], a1[5], a1[6], a1[7], hH);
  o.f3 = mk_swap(a1[8], a1[9], a1[10], a1[11], a1[12], a1[13], a1[14], a1[15], hH);
  return o;
}

// stage a (nk x nm) fp32 weight into W^T hi/lo LDS with paired b32 writes.
// lane handles (2k',m),(2k'+1,m): global reads coalesced per k-row; LDS write
// is one b32 (two adjacent shorts of row m) -> half the conflict cost of b16.
DEVFN void stage_pair(const float* W, unsigned short* wh, unsigned short* wl,
                      int nk, int nm, int stride, int tid) {
  const int npair = (nk >> 1) * nm;
  for (int p = tid; p < npair; p += 256) {
    const int m = p & (nm - 1);
    const int k2 = (p / nm) * 2;
    const float w0 = W[(size_t)k2 * nm + m];
    const float w1 = W[(size_t)(k2 + 1) * nm + m];
    *(unsigned*)&wh[m * stride + k2] = pack_hi16(w0, w1);
    *(unsigned*)&wl[m * stride + k2] = pack_hi16(lo_part(w0), lo_part(w1));
  }
}

#define ITERS 4

__global__ __launch_bounds__(256)
__attribute__((amdgpu_waves_per_eu(2, 3)))
void ngp_mlp_kernel(const float* __restrict__ x, const float* __restrict__ Win,
                    const float* __restrict__ bin, const float* __restrict__ W1,
                    const float* __restrict__ b1, const float* __restrict__ W2,
                    const float* __restrict__ b2,
                    const float* __restrict__ Wout,
                    const float* __restrict__ bout, float* __restrict__ out) {
  __shared__ __align__(16) unsigned short w1h[64 * 40], w1l[64 * 40];
  __shared__ __align__(16) unsigned short w2h[64 * 72], w2l[64 * 72];
  __shared__ __align__(16) unsigned short w3h[64 * 72], w3l[64 * 72];
  __shared__ __align__(16) unsigned short w4h[16 * 72], w4l[16 * 72];
  __shared__ __align__(16) float bsh[208];  // b_in | b1 | b2 | b_out

  const int tid = threadIdx.x;

  stage_pair(Win, w1h, w1l, 32, 64, 40, tid);
  stage_pair(W1, w2h, w2l, 64, 64, 72, tid);
  stage_pair(W2, w3h, w3l, 64, 64, 72, tid);
  stage_pair(Wout, w4h, w4l, 64, 16, 72, tid);
  if (tid < 64) {
    bsh[tid] = bin[tid];
    bsh[64 + tid] = b1[tid];
    bsh[128 + tid] = b2[tid];
    if (tid < 16) bsh[192 + tid] = bout[tid];
  }
  __syncthreads();

  const int wave = tid >> 6;
  const int lane = tid & 63;
  const int ln = lane & 31;                         // sample col / A row
  const unsigned hH = (unsigned)((lane >> 5) & 1);  // lane half
  const int kb = 8 * (int)hH;                       // k offset of this half

  for (int it = 0; it < ITERS; ++it) {
    const long srow = ((long)(blockIdx.x * ITERS + it) * 4 + wave) * 32;

    // ---- x row -> layer-1 frags ----
    Frags fr;
    {
      const float* xp = x + (size_t)(srow + ln) * 32 + kb;
      f32x4 v0 = *(const f32x4*)(xp + 0);
      f32x4 v1 = *(const f32x4*)(xp + 4);
      f32x4 v2 = *(const f32x4*)(xp + 16);
      f32x4 v3 = *(const f32x4*)(xp + 20);
      fr.f0 = mk_direct(v0, v1);
      fr.f1 = mk_direct(v2, v3);
    }

    // ---- layer 1: 32 -> 64, relu (stride 40, K=32: frags f0,f1 only) ----
    {
      f32x16 a0 = bias16(bsh, 0, (int)hH);
      f32x16 a1 = bias16(bsh, 32, (int)hH);
      const int r0 = ln * 40 + kb;
      const int r1 = (32 + ln) * 40 + kb;
      a0 = triple(w1h, w1l, r0 + 0, fr.f0, a0);
      a0 = triple(w1h, w1l, r0 + 16, fr.f1, a0);
      a1 = triple(w1h, w1l, r1 + 0, fr.f0, a1);
      a1 = triple(w1h, w1l, r1 + 16, fr.f1, a1);
      a0 = relu16(a0);
      a1 = relu16(a1);
      fr.f0 = mk_swap(a0[0], a0[1], a0[2], a0[3], a0[4], a0[5], a0[6], a0[7], hH);
      fr.f1 = mk_swap(a0[8], a0[9], a0[10], a0[11], a0[12], a0[13], a0[14], a0[15], hH);
      fr.f2 = mk_swap(a1[0], a1[1], a1[2], a1[3], a1[4], a1[5], a1[6], a1[7], hH);
      fr.f3 = mk_swap(a1[8], a1[9], a1[10], a1[11], a1[12], a1[13], a1[14], a1[15], hH);
    }

    // ---- layers 2,3: 64 -> 64, relu ----
    fr = layer64(w2h, w2l, bsh, 64, fr, ln, kb, hH);
    fr = layer64(w3h, w3l, bsh, 128, fr, ln, kb, hH);

    // ---- layer 4: 64 -> 16 (M padded to 32 by row duplication), no relu ----
    f32x16 a4;
    {
      f32x4 q0 = *(const f32x4*)&bsh[192 + 4 * (int)hH];
      f32x4 q1 = *(const f32x4*)&bsh[192 + 8 + 4 * (int)hH];
      a4[0] = q0.x; a4[1] = q0.y; a4[2] = q0.z; a4[3] = q0.w;
      a4[4] = q1.x; a4[5] = q1.y; a4[6] = q1.z; a4[7] = q1.w;
#pragma unroll
      for (int i = 8; i < 16; ++i) a4[i] = 0.0f;
    }
    {
      const int r4 = (ln & 15) * 72 + kb;
      a4 = triple(w4h, w4l, r4 + 0, fr.f0, a4);
      a4 = triple(w4h, w4l, r4 + 16, fr.f1, a4);
      a4 = triple(w4h, w4l, r4 + 32, fr.f2, a4);
      a4 = triple(w4h, w4l, r4 + 48, fr.f3, a4);
    }

    // ---- store: lane(h,n) holds row n features [4h,4h+4) and [8+4h,12+4h) ----
    {
      float* op = out + (size_t)(srow + ln) * 16 + 4 * (int)hH;
      f32x4 s0 = {a4[0], a4[1], a4[2], a4[3]};
      f32x4 s1 = {a4[4], a4[5], a4[6], a4[7]};
      *(f32x4*)(op + 0) = s0;
      *(f32x4*)(op + 8) = s1;
    }
  }
}

extern "C" void kernel_launch(void* const* d_in, const int* in_sizes, int n_in,
                              void* d_out, int out_size, void* d_ws,
                              size_t ws_size, hipStream_t stream) {
  (void)n_in;
  (void)out_size;
  (void)d_ws;
  (void)ws_size;
  const float* x = (const float*)d_in[0];
  const float* Win = (const float*)d_in[1];
  const float* bin = (const float*)d_in[2];
  const float* W1 = (const float*)d_in[3];
  const float* b1 = (const float*)d_in[4];
  const float* W2 = (const float*)d_in[5];
  const float* b2 = (const float*)d_in[6];
  const float* Wout = (const float*)d_in[7];
  const float* bout = (const float*)d_in[8];
  float* out = (float*)d_out;

  const int nrows = in_sizes[0] / 32;           // 1048576
  const int blocks = nrows / (ITERS * 4 * 32);  // 512 rows/block -> 2048
  ngp_mlp_kernel<<<blocks, 256, 0, stream>>>(x, Win, bin, W1, b1, W2, b2, Wout,
                                             bout, out);
}

// Round 4
// 459.265 us; speedup vs baseline: 1.0024x; 1.0024x over previous
//
#include <hip/hip_runtime.h>

// InstantNGP MLP: (N,32) -> [Linear+ReLU]x3 -> Linear -> (N,16), all fp32.
//
// Transposed MFMA chain, 3-product bf16 hi/lo split (fp32-accurate; absmax
// 9.8e-4 PASS R1-R3). A = W^T from LDS (bf16 hi+lo, stride 40/72 shorts,
// ds_read_b128); B = activations (col = sample); layer handoff in-register
// via pack_hi16 + permlane32_swap.
//
// R4 vs R3: FUSED rebuild+consume. R1-R3 kept a 32-reg frag aggregate live
// across layer boundaries; the allocator (pinned at 128 VGPR by something
// neither launch_bounds(,2) nor waves_per_eu(2,3) could move) spilled it:
// write-extra was exactly 264MB = 33 dw/lane/iter, re-read ~1.75x (L2+L3
// consumers) -> the whole 750MB excess + 313us. Now each 8-reg frag is
// built from the relu'd accumulator and consumed by its 6 MFMAs
// immediately (dies in ~10 instrs). Peak live ~95 VGPR: no spill possible
// even under a 128 cap. x/out paths unchanged (attribution: if WRITE_SIZE
// stays ~336MB, spill theory is falsified -> R5 stages I/O through LDS).

typedef float f32x4 __attribute__((ext_vector_type(4)));
typedef float f32x16 __attribute__((ext_vector_type(16)));
typedef short short8 __attribute__((ext_vector_type(8)));
typedef unsigned uint4v __attribute__((ext_vector_type(4)));

#define DEVFN static __device__ __forceinline__

DEVFN unsigned pack_hi16(float a, float b) {
  return (__float_as_uint(a) >> 16) | (__float_as_uint(b) & 0xffff0000u);
}
DEVFN float lo_part(float a) {
  return a - __uint_as_float(__float_as_uint(a) & 0xffff0000u);
}
DEVFN short8 s8(uint4v v) { return __builtin_bit_cast(short8, v); }

struct F8 { uint4v h, l; };   // one B-frag (hi + lo), 8 regs, short-lived
struct U2 { unsigned lo, hi; };

DEVFN U2 half_swap(unsigned q, unsigned p, unsigned laneHi) {
#if __has_builtin(__builtin_amdgcn_permlane32_swap)
  (void)laneHi;
  auto r = __builtin_amdgcn_permlane32_swap(q, p, false, false);
  return U2{(unsigned)r[0], (unsigned)r[1]};
#else
  unsigned qs = (unsigned)__shfl_xor((int)q, 32, 64);
  unsigned ps = (unsigned)__shfl_xor((int)p, 32, 64);
  return U2{laneHi ? ps : q, laneHi ? p : qs};
#endif
}

// 8 C-regs of one 32x32 tile-half -> B frag for the next layer (R1-verified)
DEVFN F8 mk_swap(float c0, float c1, float c2, float c3, float c4, float c5,
                 float c6, float c7, unsigned laneHi) {
  U2 a = half_swap(pack_hi16(c0, c1), pack_hi16(c4, c5), laneHi);
  U2 b = half_swap(pack_hi16(c2, c3), pack_hi16(c6, c7), laneHi);
  U2 c = half_swap(pack_hi16(lo_part(c0), lo_part(c1)),
                   pack_hi16(lo_part(c4), lo_part(c5)), laneHi);
  U2 d = half_swap(pack_hi16(lo_part(c2), lo_part(c3)),
                   pack_hi16(lo_part(c6), lo_part(c7)), laneHi);
  F8 f;
  f.h = (uint4v){a.lo, b.lo, a.hi, b.hi};
  f.l = (uint4v){c.lo, d.lo, c.hi, d.hi};
  return f;
}

// x row chunk (8 floats) -> layer-1 B frag (no cross-lane)
DEVFN F8 mk_direct(f32x4 a, f32x4 b) {
  F8 f;
  f.h = (uint4v){pack_hi16(a.x, a.y), pack_hi16(a.z, a.w),
                 pack_hi16(b.x, b.y), pack_hi16(b.z, b.w)};
  f.l = (uint4v){pack_hi16(lo_part(a.x), lo_part(a.y)),
                 pack_hi16(lo_part(a.z), lo_part(a.w)),
                 pack_hi16(lo_part(b.x), lo_part(b.y)),
                 pack_hi16(lo_part(b.z), lo_part(b.w))};
  return f;
}

DEVFN f32x16 mfma32(short8 a, short8 b, f32x16 c) {
  return __builtin_amdgcn_mfma_f32_32x32x16_bf16(a, b, c, 0, 0, 0);
}

// 3-product K=16 step: acc += W.lo*B.hi + W.hi*B.lo + W.hi*B.hi
DEVFN f32x16 triple(const unsigned short* wh, const unsigned short* wl, int off,
                    F8 b, f32x16 acc) {
  short8 ah = *(const short8*)&wh[off];
  short8 al = *(const short8*)&wl[off];
  acc = mfma32(al, s8(b.h), acc);
  acc = mfma32(ah, s8(b.l), acc);
  acc = mfma32(ah, s8(b.h), acc);
  return acc;
}

DEVFN f32x16 bias16(const float* bsh, int boff, int hH) {
  f32x16 bi;
#pragma unroll
  for (int cq = 0; cq < 4; ++cq) {
    f32x4 bb = *(const f32x4*)&bsh[boff + 8 * cq + 4 * hH];
    bi[4 * cq + 0] = bb.x;
    bi[4 * cq + 1] = bb.y;
    bi[4 * cq + 2] = bb.z;
    bi[4 * cq + 3] = bb.w;
  }
  return bi;
}

DEVFN f32x16 relu16(f32x16 v) {
#pragma unroll
  for (int i = 0; i < 16; ++i) v[i] = fmaxf(v[i], 0.0f);
  return v;
}

// Fused 64->64 layer: relu inputs, then per k-slice build the 8-reg frag and
// consume it immediately (6 MFMAs). a0,a1 (features [0,32)/[32,64)) updated
// in place. Frag ka source: ka0=a0[0:8], ka1=a0[8:16], ka2=a1[0:8],
// ka3=a1[8:16]; consumed at k-offset 16*ka (R1-verified mapping).
DEVFN void layer64(const unsigned short* wh, const unsigned short* wl,
                   const float* bsh, int boff, f32x16& a0, f32x16& a1, int r0,
                   int r1, int hH) {
  a0 = relu16(a0);
  a1 = relu16(a1);
  f32x16 n0 = bias16(bsh, boff, hH);
  f32x16 n1 = bias16(bsh, boff + 32, hH);
  const unsigned laneHi = (unsigned)hH;
  {
    F8 f = mk_swap(a0[0], a0[1], a0[2], a0[3], a0[4], a0[5], a0[6], a0[7], laneHi);
    n0 = triple(wh, wl, r0 + 0, f, n0);
    n1 = triple(wh, wl, r1 + 0, f, n1);
  }
  {
    F8 f = mk_swap(a0[8], a0[9], a0[10], a0[11], a0[12], a0[13], a0[14], a0[15], laneHi);
    n0 = triple(wh, wl, r0 + 16, f, n0);
    n1 = triple(wh, wl, r1 + 16, f, n1);
  }
  {
    F8 f = mk_swap(a1[0], a1[1], a1[2], a1[3], a1[4], a1[5], a1[6], a1[7], laneHi);
    n0 = triple(wh, wl, r0 + 32, f, n0);
    n1 = triple(wh, wl, r1 + 32, f, n1);
  }
  {
    F8 f = mk_swap(a1[8], a1[9], a1[10], a1[11], a1[12], a1[13], a1[14], a1[15], laneHi);
    n0 = triple(wh, wl, r0 + 48, f, n0);
    n1 = triple(wh, wl, r1 + 48, f, n1);
  }
  a0 = n0;
  a1 = n1;
}

// stage (nk x nm) fp32 weight into W^T hi/lo LDS, paired b32 writes
DEVFN void stage_pair(const float* W, unsigned short* wh, unsigned short* wl,
                      int nk, int nm, int stride, int tid) {
  const int npair = (nk >> 1) * nm;
  for (int p = tid; p < npair; p += 256) {
    const int m = p & (nm - 1);
    const int k2 = (p / nm) * 2;
    const float w0 = W[(size_t)k2 * nm + m];
    const float w1 = W[(size_t)(k2 + 1) * nm + m];
    *(unsigned*)&wh[m * stride + k2] = pack_hi16(w0, w1);
    *(unsigned*)&wl[m * stride + k2] = pack_hi16(lo_part(w0), lo_part(w1));
  }
}

#define ITERS 4

__global__ __launch_bounds__(256, 2) void ngp_mlp_kernel(
    const float* __restrict__ x, const float* __restrict__ Win,
    const float* __restrict__ bin, const float* __restrict__ W1,
    const float* __restrict__ b1, const float* __restrict__ W2,
    const float* __restrict__ b2, const float* __restrict__ Wout,
    const float* __restrict__ bout, float* __restrict__ out) {
  __shared__ __align__(16) unsigned short w1h[64 * 40], w1l[64 * 40];
  __shared__ __align__(16) unsigned short w2h[64 * 72], w2l[64 * 72];
  __shared__ __align__(16) unsigned short w3h[64 * 72], w3l[64 * 72];
  __shared__ __align__(16) unsigned short w4h[16 * 72], w4l[16 * 72];
  __shared__ __align__(16) float bsh[208];  // b_in | b1 | b2 | b_out

  const int tid = threadIdx.x;

  stage_pair(Win, w1h, w1l, 32, 64, 40, tid);
  stage_pair(W1, w2h, w2l, 64, 64, 72, tid);
  stage_pair(W2, w3h, w3l, 64, 64, 72, tid);
  stage_pair(Wout, w4h, w4l, 64, 16, 72, tid);
  if (tid < 64) {
    bsh[tid] = bin[tid];
    bsh[64 + tid] = b1[tid];
    bsh[128 + tid] = b2[tid];
    if (tid < 16) bsh[192 + tid] = bout[tid];
  }
  __syncthreads();

  const int wave = tid >> 6;
  const int lane = tid & 63;
  const int ln = lane & 31;            // sample col / A row
  const int hH = (lane >> 5) & 1;      // lane half
  const int kb = 8 * hH;               // k offset of this half
  const unsigned laneHi = (unsigned)hH;

  const int r40a = ln * 40 + kb, r40b = (32 + ln) * 40 + kb;
  const int r72a = ln * 72 + kb, r72b = (32 + ln) * 72 + kb;
  const int r72o = (ln & 15) * 72 + kb;

  for (int it = 0; it < ITERS; ++it) {
    const long srow = ((long)(blockIdx.x * ITERS + it) * 4 + wave) * 32;

    f32x16 a0, a1;
    // ---- layer 1: 32 -> 64 (frags straight from x, consumed immediately) --
    {
      const float* xp = x + (size_t)(srow + ln) * 32 + kb;
      a0 = bias16(bsh, 0, hH);
      a1 = bias16(bsh, 32, hH);
      {
        f32x4 v0 = *(const f32x4*)(xp + 0);
        f32x4 v1 = *(const f32x4*)(xp + 4);
        F8 f = mk_direct(v0, v1);
        a0 = triple(w1h, w1l, r40a + 0, f, a0);
        a1 = triple(w1h, w1l, r40b + 0, f, a1);
      }
      {
        f32x4 v2 = *(const f32x4*)(xp + 16);
        f32x4 v3 = *(const f32x4*)(xp + 20);
        F8 f = mk_direct(v2, v3);
        a0 = triple(w1h, w1l, r40a + 16, f, a0);
        a1 = triple(w1h, w1l, r40b + 16, f, a1);
      }
    }

    // ---- layers 2,3: 64 -> 64 (fused relu+rebuild+consume) ----
    layer64(w2h, w2l, bsh, 64, a0, a1, r72a, r72b, hH);
    layer64(w3h, w3l, bsh, 128, a0, a1, r72a, r72b, hH);

    // ---- layer 4: 64 -> 16 (M padded to 32 by row duplication), no relu ----
    f32x16 a4;
    {
      a0 = relu16(a0);
      a1 = relu16(a1);
      f32x4 q0 = *(const f32x4*)&bsh[192 + 4 * hH];
      f32x4 q1 = *(const f32x4*)&bsh[192 + 8 + 4 * hH];
      a4[0] = q0.x; a4[1] = q0.y; a4[2] = q0.z; a4[3] = q0.w;
      a4[4] = q1.x; a4[5] = q1.y; a4[6] = q1.z; a4[7] = q1.w;
#pragma unroll
      for (int i = 8; i < 16; ++i) a4[i] = 0.0f;
      {
        F8 f = mk_swap(a0[0], a0[1], a0[2], a0[3], a0[4], a0[5], a0[6], a0[7], laneHi);
        a4 = triple(w4h, w4l, r72o + 0, f, a4);
      }
      {
        F8 f = mk_swap(a0[8], a0[9], a0[10], a0[11], a0[12], a0[13], a0[14], a0[15], laneHi);
        a4 = triple(w4h, w4l, r72o + 16, f, a4);
      }
      {
        F8 f = mk_swap(a1[0], a1[1], a1[2], a1[3], a1[4], a1[5], a1[6], a1[7], laneHi);
        a4 = triple(w4h, w4l, r72o + 32, f, a4);
      }
      {
        F8 f = mk_swap(a1[8], a1[9], a1[10], a1[11], a1[12], a1[13], a1[14], a1[15], laneHi);
        a4 = triple(w4h, w4l, r72o + 48, f, a4);
      }
    }

    // ---- store: lane(h,n) holds row n feats [4h,4h+4) and [8+4h,12+4h) ----
    {
      float* op = out + (size_t)(srow + ln) * 16 + 4 * hH;
      f32x4 s0 = {a4[0], a4[1], a4[2], a4[3]};
      f32x4 s1 = {a4[4], a4[5], a4[6], a4[7]};
      *(f32x4*)(op + 0) = s0;
      *(f32x4*)(op + 8) = s1;
    }
  }
}

extern "C" void kernel_launch(void* const* d_in, const int* in_sizes, int n_in,
                              void* d_out, int out_size, void* d_ws,
                              size_t ws_size, hipStream_t stream) {
  (void)n_in;
  (void)out_size;
  (void)d_ws;
  (void)ws_size;
  const float* x = (const float*)d_in[0];
  const float* Win = (const float*)d_in[1];
  const float* bin = (const float*)d_in[2];
  const float* W1 = (const float*)d_in[3];
  const float* b1 = (const float*)d_in[4];
  const float* W2 = (const float*)d_in[5];
  const float* b2 = (const float*)d_in[6];
  const float* Wout = (const float*)d_in[7];
  const float* bout = (const float*)d_in[8];
  float* out = (float*)d_out;

  const int nrows = in_sizes[0] / 32;           // 1048576
  const int blocks = nrows / (ITERS * 4 * 32);  // 512 rows/block -> 2048
  ngp_mlp_kernel<<<blocks, 256, 0, stream>>>(x, Win, bin, W1, b1, W2, b2, Wout,
                                             bout, out);
}